// Round 5
// baseline (1618.454 us; speedup 1.0000x reference)
//
#include <hip/hip_runtime.h>
#include <hip/hip_bf16.h>
#include <stdint.h>

// ---------- types ----------
using bf16x8 = __attribute__((ext_vector_type(8))) short;
using f32x4  = __attribute__((ext_vector_type(4))) float;

__device__ __forceinline__ unsigned short f2b(float f) {
  unsigned u = __float_as_uint(f);
  u = u + 0x7FFFu + ((u >> 16) & 1u);   // RNE
  return (unsigned short)(u >> 16);
}
__device__ __forceinline__ float b2f(unsigned short s) {
  return __uint_as_float(((unsigned)s) << 16);
}

// ---------- problem constants ----------
#define N_NC 10240
#define N_D  5120
#define E_NC 327680
#define E_D  163840
#define F_NC 599
#define F_D  91
#define KP_NC 608
#define KP_D  96
#define TOT_NODES 46080               // 3*10240 + 3*5120
#define TOT_EDGES 1474560             // 3*E_NC + 3*E_D
#define MW 160                        // mask words per user row (5120/32)

// ---------- utility: zero an int buffer ----------
__global__ __launch_bounds__(256) void k_zero(int* p, int n) {
  int t = blockIdx.x * 256 + threadIdx.x;
  if (t < n) p[t] = 0;
}

// ---------- prep: transpose + bf16-split weights ----------
__global__ __launch_bounds__(256) void k_prep(const float* Wnc, const float* Wd,
                       unsigned short* WTnc_hi, unsigned short* WTnc_lo,
                       unsigned short* WTd_hi, unsigned short* WTd_lo) {
  int tid = blockIdx.x * blockDim.x + threadIdx.x;
  int stride = gridDim.x * blockDim.x;
  for (int i = tid; i < 64 * KP_NC; i += stride) {
    int d = i / KP_NC, k = i % KP_NC;
    float w = (k < F_NC) ? Wnc[k * 64 + d] : 0.0f;
    unsigned short h = f2b(w);
    WTnc_hi[i] = h;
    WTnc_lo[i] = f2b(w - b2f(h));
  }
  for (int i = tid; i < 64 * KP_D; i += stride) {
    int d = i / KP_D, k = i % KP_D;
    float w = (k < F_D) ? Wd[k * 64 + d] : 0.0f;
    unsigned short h = f2b(w);
    WTd_hi[i] = h;
    WTd_lo[i] = f2b(w - b2f(h));
  }
}

// ---------- encoder: h = x@W + b, capsule-l2norm -> xnorm (f32) ----------
template <int F, int KPAD>
__global__ __launch_bounds__(256) void k_encoder(const float* __restrict__ x,
    const unsigned short* __restrict__ WT_hi, const unsigned short* __restrict__ WT_lo,
    const float* __restrict__ bias, float* __restrict__ out) {
  int wave = threadIdx.x >> 6;
  int tile = blockIdx.x * 4 + wave;
  int l = threadIdx.x & 63;
  int h = l >> 4, r0 = l & 15;
  int m0 = tile * 16;

  f32x4 acc[4] = {{0,0,0,0},{0,0,0,0},{0,0,0,0},{0,0,0,0}};
  const float* xrow = x + (size_t)(m0 + r0) * F;

  for (int ks = 0; ks < KPAD / 32; ++ks) {
    int k0 = ks * 32 + h * 8;
    bf16x8 ah, al;
#pragma unroll
    for (int j = 0; j < 8; ++j) {
      int k = k0 + j;
      float v = (k < F) ? xrow[k] : 0.0f;
      unsigned short hb = f2b(v);
      ah[j] = (short)hb;
      al[j] = (short)f2b(v - b2f(hb));
    }
#pragma unroll
    for (int nt = 0; nt < 4; ++nt) {
      bf16x8 bh = *(const bf16x8*)(WT_hi + (nt * 16 + r0) * KPAD + k0);
      bf16x8 bl = *(const bf16x8*)(WT_lo + (nt * 16 + r0) * KPAD + k0);
      acc[nt] = __builtin_amdgcn_mfma_f32_16x16x32_bf16(ah, bh, acc[nt], 0, 0, 0);
      acc[nt] = __builtin_amdgcn_mfma_f32_16x16x32_bf16(ah, bl, acc[nt], 0, 0, 0);
      acc[nt] = __builtin_amdgcn_mfma_f32_16x16x32_bf16(al, bh, acc[nt], 0, 0, 0);
    }
  }
#pragma unroll
  for (int nt = 0; nt < 4; ++nt) {
    float bv = bias[nt * 16 + r0];
#pragma unroll
    for (int r = 0; r < 4; ++r) acc[nt][r] += bv;
  }
#pragma unroll
  for (int r = 0; r < 4; ++r) {
    float ss0 = acc[0][r] * acc[0][r] + acc[1][r] * acc[1][r];
    float ss1 = acc[2][r] * acc[2][r] + acc[3][r] * acc[3][r];
#pragma unroll
    for (int m = 1; m < 16; m <<= 1) { ss0 += __shfl_xor(ss0, m); ss1 += __shfl_xor(ss1, m); }
    float s0 = 1.0f / fmaxf(sqrtf(ss0), 1e-12f);
    float s1 = 1.0f / fmaxf(sqrtf(ss1), 1e-12f);
    float* o = out + (size_t)(m0 + 4 * h + r) * 64;
    o[ 0 + r0] = acc[0][r] * s0;
    o[16 + r0] = acc[1][r] * s0;
    o[32 + r0] = acc[2][r] * s1;
    o[48 + r0] = acc[3][r] * s1;
  }
}

// ---------- CSR build ----------
__device__ __forceinline__ void seg_decode(int t,
    const int* e0, const int* e1, const int* e2,
    const int* e3, const int* e4, const int* e5,
    const int** ep, int* el, int* noff, int* En) {
  if (t < 3 * E_NC) {
    int g = t / E_NC; *el = t - g * E_NC; *En = E_NC; *noff = g * N_NC;
    *ep = (g == 0) ? e0 : (g == 1) ? e1 : e2;
  } else {
    int u = t - 3 * E_NC;
    int g = u / E_D; *el = u - g * E_D; *En = E_D; *noff = 3 * N_NC + g * N_D;
    *ep = (g == 0) ? e3 : (g == 1) ? e4 : e5;
  }
}

__global__ __launch_bounds__(256) void k_hist(const int* e0, const int* e1, const int* e2,
                       const int* e3, const int* e4, const int* e5, int* cnt) {
  int t = blockIdx.x * blockDim.x + threadIdx.x;
  const int* ep; int el, noff, En;
  seg_decode(t, e0, e1, e2, e3, e4, e5, &ep, &el, &noff, &En);
  int trg = ep[En + el];
  atomicAdd(&cnt[noff + trg], 1);
}

__global__ __launch_bounds__(256) void k_scan1(const int* cnt, int* incl, int* bsum) {
  __shared__ int sh[256];
  int g = blockIdx.x * 256 + threadIdx.x;
  int v = cnt[g];
  sh[threadIdx.x] = v;
  __syncthreads();
  for (int off = 1; off < 256; off <<= 1) {
    int t = (threadIdx.x >= off) ? sh[threadIdx.x - off] : 0;
    __syncthreads();
    sh[threadIdx.x] += t;
    __syncthreads();
  }
  incl[g] = sh[threadIdx.x];
  if (threadIdx.x == 255) bsum[blockIdx.x] = sh[255];
}

__global__ __launch_bounds__(256) void k_scan2(int* bsum) {   // 1 block; 180 partials
  __shared__ int sh[256];
  int t = threadIdx.x;
  int v = (t < 180) ? bsum[t] : 0;
  sh[t] = v;
  __syncthreads();
  for (int off = 1; off < 256; off <<= 1) {
    int x = (t >= off) ? sh[t - off] : 0;
    __syncthreads();
    sh[t] += x;
    __syncthreads();
  }
  if (t < 180) bsum[t] = sh[t] - v;    // exclusive
}

__global__ __launch_bounds__(256) void k_scan3(const int* incl, const int* cnt,
                                               const int* bsum, int* rowptr, int* cursor) {
  int g = blockIdx.x * 256 + threadIdx.x;
  int x = incl[g] + bsum[blockIdx.x];
  rowptr[g + 1] = x;
  cursor[g] = x - cnt[g];
  if (g == 0) rowptr[0] = 0;
}

__global__ __launch_bounds__(256) void k_scatter(const int* e0, const int* e1, const int* e2,
                          const int* e3, const int* e4, const int* e5,
                          int* cursor, int* csr) {
  int t = blockIdx.x * blockDim.x + threadIdx.x;
  const int* ep; int el, noff, En;
  seg_decode(t, e0, e1, e2, e3, e4, e5, &ep, &el, &noff, &En);
  int src = ep[el];
  int trg = ep[En + el];
  int pos = atomicAdd(&cursor[noff + trg], 1);
  csr[pos] = src;
}

// ---------- routing: 3 iterations, node-local (32 lanes per node, 2 dims/lane) ----------
template <int NPG>
__global__ __launch_bounds__(256) void k_route(const float* __restrict__ xnorm, float* __restrict__ cfin,
    const int* __restrict__ row_ptr, const int* __restrict__ csr, int rpOff) {
  int node = (blockIdx.x * blockDim.x + threadIdx.x) >> 5;
  int q = threadIdx.x & 31;
  int graph = node / NPG;
  size_t gb32 = (size_t)graph * NPG * 32;
  int rp0 = row_ptr[rpOff + node], rp1 = row_ptr[rpOff + node + 1];
  const float2* xn2 = (const float2*)xnorm;
  float2 c = xn2[(size_t)node * 32 + q];
  for (int it = 0; it < 3; ++it) {
    float2 acc = c;
    for (int e = rp0; e < rp1; ++e) {
      int s = csr[e];
      float2 z = xn2[gb32 + (size_t)s * 32 + q];
      float part = z.x * c.x + z.y * c.y;
      part += __shfl_xor(part, 1);
      part += __shfl_xor(part, 2);
      part += __shfl_xor(part, 4);
      part += __shfl_xor(part, 8);
      float other = __shfl_xor(part, 16);
      float p = 1.0f / (1.0f + __expf(other - part));
      acc.x += p * z.x;
      acc.y += p * z.y;
    }
    float ss = acc.x * acc.x + acc.y * acc.y;
    ss += __shfl_xor(ss, 1);
    ss += __shfl_xor(ss, 2);
    ss += __shfl_xor(ss, 4);
    ss += __shfl_xor(ss, 8);
    float sc = 1.0f / fmaxf(sqrtf(ss), 1e-12f);
    c.x = acc.x * sc;
    c.y = acc.y * sc;
  }
  ((float2*)cfin)[(size_t)node * 32 + q] = c;
}

// ---------- attention fuse + tu = relu(fused@Wj+bj); emit bf16 row/col copies ----------
__global__ __launch_bounds__(256) void k_attn(const float* __restrict__ cfin, int n,
    const float* __restrict__ W1, const float* __restrict__ b1, const float* __restrict__ W2,
    const float* __restrict__ Wj, const float* __restrict__ bj,
    unsigned short* bfr, unsigned short* bfT, float* tu) {
  __shared__ float zs[4][3][64];
  __shared__ float fs[4][64];
  int wave = threadIdx.x >> 6, l = threadIdx.x & 63;
  int node = blockIdx.x * 4 + wave;
#pragma unroll
  for (int j = 0; j < 3; ++j)
    zs[wave][j][l] = cfin[((size_t)j * n + node) * 64 + l];
  __syncthreads();
  float w[3];
#pragma unroll
  for (int j = 0; j < 3; ++j) {
    float y = b1[l];
    for (int k = 0; k < 64; ++k) y += zs[wave][j][k] * W1[k * 64 + l];
    y = (y > 0.0f) ? y : 0.2f * y;
    float t = y * W2[l];
#pragma unroll
    for (int m = 1; m < 64; m <<= 1) t += __shfl_xor(t, m);
    w[j] = t;
  }
  float mx = fmaxf(w[0], fmaxf(w[1], w[2]));
  float e0 = __expf(w[0] - mx), e1 = __expf(w[1] - mx), e2 = __expf(w[2] - mx);
  float inv = 1.0f / (e0 + e1 + e2);
  float be0 = e0 * inv + 1e-6f, be1 = e1 * inv + 1e-6f, be2 = e2 * inv + 1e-6f;
  float bs = 1.0f / (be0 + be1 + be2);
  be0 *= bs; be1 *= bs; be2 *= bs;
  float o = be0 * zs[wave][0][l] + be1 * zs[wave][1][l] + be2 * zs[wave][2][l];
  fs[wave][l] = o;
  __syncthreads();
  bfr[(size_t)node * 64 + l] = f2b(o);
  bfT[(size_t)l * n + node] = f2b(o);
  float t = bj[l];
  for (int k = 0; k < 64; ++k) t += fs[wave][k] * Wj[k * 64 + l];
  tu[(size_t)node * 64 + l] = fmaxf(t, 0.0f);
}

// ---------- A>0 bitmask: mb[u][m/32] bit m%32 ----------
__global__ __launch_bounds__(256) void k_mask(const float* __restrict__ A, unsigned int* mb) {
  int wid = (blockIdx.x * blockDim.x + threadIdx.x) >> 6;   // global wave id
  int l = threadIdx.x & 63;
  int row = wid / 10, seg = wid % 10;                       // 512 cols per wave
  const float4* ap = (const float4*)(A + (size_t)row * 5120 + seg * 512 + l * 8);
  float4 v0 = ap[0], v1 = ap[1];
  unsigned b = (unsigned)(v0.x > 0.0f)       | ((unsigned)(v0.y > 0.0f) << 1)
             | ((unsigned)(v0.z > 0.0f) << 2) | ((unsigned)(v0.w > 0.0f) << 3)
             | ((unsigned)(v1.x > 0.0f) << 4) | ((unsigned)(v1.y > 0.0f) << 5)
             | ((unsigned)(v1.z > 0.0f) << 6) | ((unsigned)(v1.w > 0.0f) << 7);
  b |= ((unsigned)__shfl_xor((int)b, 1)) << 8;
  b |= ((unsigned)__shfl_xor((int)b, 2)) << 16;
  if ((l & 3) == 0) mb[row * MW + seg * 16 + (l >> 2)] = b;
}

// ---------- joint masked-softmax attention (4 waves split Nk) ----------
// out (split-bf16 hi/lo pair) = tu + softmax(QK^T, mask) @ V
template <bool MT>
__global__ __launch_bounds__(256) void k_joint(const unsigned short* __restrict__ qbf,
    const unsigned short* __restrict__ kbf, const unsigned short* __restrict__ vT, int Nk,
    const unsigned int* __restrict__ mb, const float* __restrict__ tu,
    unsigned short* outh, unsigned short* outl) {
  __shared__ float st[4][16][2];
  __shared__ __align__(16) unsigned short pl[4][16][32];
  __shared__ float oc[4][16][64];
  int wave = threadIdx.x >> 6, l = threadIdx.x & 63;
  int h = l >> 4, r0 = l & 15;
  int q0 = blockIdx.x * 16;
  int seg = Nk >> 2;
  int m_lo = wave * seg, m_hi = m_lo + seg;

  bf16x8 a0 = *(const bf16x8*)(qbf + (size_t)(q0 + r0) * 64 + h * 8);
  bf16x8 a1 = *(const bf16x8*)(qbf + (size_t)(q0 + r0) * 64 + 32 + h * 8);

  float lm[4], ls[4];
#pragma unroll
  for (int r = 0; r < 4; ++r) { lm[r] = -1e30f; ls[r] = 0.0f; }

  for (int m0 = m_lo; m0 < m_hi; m0 += 32) {
    f32x4 s0 = {0,0,0,0}, s1 = {0,0,0,0};
    {
      bf16x8 b00 = *(const bf16x8*)(kbf + (size_t)(m0 + r0) * 64 + h * 8);
      bf16x8 b10 = *(const bf16x8*)(kbf + (size_t)(m0 + 16 + r0) * 64 + h * 8);
      s0 = __builtin_amdgcn_mfma_f32_16x16x32_bf16(a0, b00, s0, 0, 0, 0);
      s1 = __builtin_amdgcn_mfma_f32_16x16x32_bf16(a0, b10, s1, 0, 0, 0);
      bf16x8 b01 = *(const bf16x8*)(kbf + (size_t)(m0 + r0) * 64 + 32 + h * 8);
      bf16x8 b11 = *(const bf16x8*)(kbf + (size_t)(m0 + 16 + r0) * 64 + 32 + h * 8);
      s0 = __builtin_amdgcn_mfma_f32_16x16x32_bf16(a1, b01, s0, 0, 0, 0);
      s1 = __builtin_amdgcn_mfma_f32_16x16x32_bf16(a1, b11, s1, 0, 0, 0);
    }
    unsigned w0 = 0, w1 = 0;
    if (MT) {
      w0 = mb[(size_t)(m0 + r0) * MW + (q0 >> 5)];
      w1 = mb[(size_t)(m0 + 16 + r0) * MW + (q0 >> 5)];
    }
#pragma unroll
    for (int r = 0; r < 4; ++r) {
      float e0, e1;
      if (MT) {
        int bit = (q0 & 31) + 4 * h + r;
        e0 = ((w0 >> bit) & 1u) ? s0[r] : -1e9f;
        e1 = ((w1 >> bit) & 1u) ? s1[r] : -1e9f;
      } else {
        unsigned wr = mb[(size_t)(q0 + 4 * h + r) * MW + (m0 >> 5)];
        e0 = ((wr >> r0) & 1u) ? s0[r] : -1e9f;
        e1 = ((wr >> (r0 + 16)) & 1u) ? s1[r] : -1e9f;
      }
      float nm = fmaxf(lm[r], fmaxf(e0, e1));
      ls[r] = ls[r] * __expf(lm[r] - nm) + __expf(e0 - nm) + __expf(e1 - nm);
      lm[r] = nm;
    }
  }
#pragma unroll
  for (int r = 0; r < 4; ++r) {
#pragma unroll
    for (int m = 1; m < 16; m <<= 1) {
      float om = __shfl_xor(lm[r], m), os = __shfl_xor(ls[r], m);
      float nm = fmaxf(lm[r], om);
      ls[r] = ls[r] * __expf(lm[r] - nm) + os * __expf(om - nm);
      lm[r] = nm;
    }
  }
  if (r0 == 0) {
#pragma unroll
    for (int r = 0; r < 4; ++r) { st[wave][4 * h + r][0] = lm[r]; st[wave][4 * h + r][1] = ls[r]; }
  }
  __syncthreads();
  float M[4], S[4];
#pragma unroll
  for (int r = 0; r < 4; ++r) {
    int row = 4 * h + r;
    float mm = fmaxf(fmaxf(st[0][row][0], st[1][row][0]), fmaxf(st[2][row][0], st[3][row][0]));
    float s = st[0][row][1] * __expf(st[0][row][0] - mm)
            + st[1][row][1] * __expf(st[1][row][0] - mm)
            + st[2][row][1] * __expf(st[2][row][0] - mm)
            + st[3][row][1] * __expf(st[3][row][0] - mm);
    M[r] = mm; S[r] = s;
  }

  f32x4 o[4] = {{0,0,0,0},{0,0,0,0},{0,0,0,0},{0,0,0,0}};
  for (int m0 = m_lo; m0 < m_hi; m0 += 32) {
    f32x4 s0 = {0,0,0,0}, s1 = {0,0,0,0};
    {
      bf16x8 b00 = *(const bf16x8*)(kbf + (size_t)(m0 + r0) * 64 + h * 8);
      bf16x8 b10 = *(const bf16x8*)(kbf + (size_t)(m0 + 16 + r0) * 64 + h * 8);
      s0 = __builtin_amdgcn_mfma_f32_16x16x32_bf16(a0, b00, s0, 0, 0, 0);
      s1 = __builtin_amdgcn_mfma_f32_16x16x32_bf16(a0, b10, s1, 0, 0, 0);
      bf16x8 b01 = *(const bf16x8*)(kbf + (size_t)(m0 + r0) * 64 + 32 + h * 8);
      bf16x8 b11 = *(const bf16x8*)(kbf + (size_t)(m0 + 16 + r0) * 64 + 32 + h * 8);
      s0 = __builtin_amdgcn_mfma_f32_16x16x32_bf16(a1, b01, s0, 0, 0, 0);
      s1 = __builtin_amdgcn_mfma_f32_16x16x32_bf16(a1, b11, s1, 0, 0, 0);
    }
    unsigned w0 = 0, w1 = 0;
    if (MT) {
      w0 = mb[(size_t)(m0 + r0) * MW + (q0 >> 5)];
      w1 = mb[(size_t)(m0 + 16 + r0) * MW + (q0 >> 5)];
    }
#pragma unroll
    for (int r = 0; r < 4; ++r) {
      float e0, e1;
      if (MT) {
        int bit = (q0 & 31) + 4 * h + r;
        e0 = ((w0 >> bit) & 1u) ? s0[r] : -1e9f;
        e1 = ((w1 >> bit) & 1u) ? s1[r] : -1e9f;
      } else {
        unsigned wr = mb[(size_t)(q0 + 4 * h + r) * MW + (m0 >> 5)];
        e0 = ((wr >> r0) & 1u) ? s0[r] : -1e9f;
        e1 = ((wr >> (r0 + 16)) & 1u) ? s1[r] : -1e9f;
      }
      pl[wave][4 * h + r][r0]      = f2b(__expf(e0 - M[r]));
      pl[wave][4 * h + r][r0 + 16] = f2b(__expf(e1 - M[r]));
    }
    __syncthreads();
    bf16x8 pa = *(const bf16x8*)(&pl[wave][r0][h * 8]);
#pragma unroll
    for (int nt = 0; nt < 4; ++nt) {
      bf16x8 bv = *(const bf16x8*)(vT + (size_t)(nt * 16 + r0) * Nk + m0 + h * 8);
      o[nt] = __builtin_amdgcn_mfma_f32_16x16x32_bf16(pa, bv, o[nt], 0, 0, 0);
    }
  }
  float inv[4];
#pragma unroll
  for (int r = 0; r < 4; ++r) inv[r] = 1.0f / S[r];
#pragma unroll
  for (int nt = 0; nt < 4; ++nt)
#pragma unroll
    for (int r = 0; r < 4; ++r)
      oc[wave][4 * h + r][nt * 16 + r0] = o[nt][r] * inv[r];
  __syncthreads();
  for (int e = threadIdx.x; e < 1024; e += 256) {
    int row = e >> 6, col = e & 63;
    float v = oc[0][row][col] + oc[1][row][col] + oc[2][row][col] + oc[3][row][col];
    v += tu[(size_t)(q0 + row) * 64 + col];
    unsigned short hb = f2b(v);
    outh[(size_t)(q0 + row) * 64 + col] = hb;
    outl[(size_t)(q0 + row) * 64 + col] = f2b(v - b2f(hb));
  }
}

// ---------- decoder: out[i][u] = sum_d I[i][d]*U[u][d], split-bf16 inputs, FLOAT32 out ----------
__global__ __launch_bounds__(256) void k_dec(const unsigned short* __restrict__ Ih,
    const unsigned short* __restrict__ Il,
    const unsigned short* __restrict__ Uh, const unsigned short* __restrict__ Ul,
    float* __restrict__ out) {
  int w = (blockIdx.x * blockDim.x + threadIdx.x) >> 6;
  int l = threadIdx.x & 63, h = l >> 4, r0 = l & 15;
  int i0 = (w / 160) * 16, u0 = (w % 160) * 64;
  size_t abase = (size_t)(i0 + r0) * 64 + h * 8;
  bf16x8 a0h = *(const bf16x8*)(Ih + abase);
  bf16x8 a1h = *(const bf16x8*)(Ih + abase + 32);
  bf16x8 a0l = *(const bf16x8*)(Il + abase);
  bf16x8 a1l = *(const bf16x8*)(Il + abase + 32);
#pragma unroll
  for (int nt = 0; nt < 4; ++nt) {
    size_t bbase = (size_t)(u0 + nt * 16 + r0) * 64 + h * 8;
    bf16x8 b0h = *(const bf16x8*)(Uh + bbase);
    bf16x8 b1h = *(const bf16x8*)(Uh + bbase + 32);
    bf16x8 b0l = *(const bf16x8*)(Ul + bbase);
    bf16x8 b1l = *(const bf16x8*)(Ul + bbase + 32);
    f32x4 acc = {0,0,0,0};
    acc = __builtin_amdgcn_mfma_f32_16x16x32_bf16(a0h, b0h, acc, 0, 0, 0);
    acc = __builtin_amdgcn_mfma_f32_16x16x32_bf16(a1h, b1h, acc, 0, 0, 0);
    acc = __builtin_amdgcn_mfma_f32_16x16x32_bf16(a0h, b0l, acc, 0, 0, 0);
    acc = __builtin_amdgcn_mfma_f32_16x16x32_bf16(a1h, b1l, acc, 0, 0, 0);
    acc = __builtin_amdgcn_mfma_f32_16x16x32_bf16(a0l, b0h, acc, 0, 0, 0);
    acc = __builtin_amdgcn_mfma_f32_16x16x32_bf16(a1l, b1h, acc, 0, 0, 0);
#pragma unroll
    for (int r = 0; r < 4; ++r)
      out[(size_t)(i0 + 4 * h + r) * 10240 + u0 + nt * 16 + r0] = acc[r];
  }
}

// ---------- host ----------
extern "C" void kernel_launch(void* const* d_in, const int* in_sizes, int n_in,
                              void* d_out, int out_size, void* d_ws, size_t ws_size,
                              hipStream_t stream) {
  const float* NC1 = (const float*)d_in[0];
  const float* NC2 = (const float*)d_in[1];
  const float* NC3 = (const float*)d_in[2];
  const float* Dx1 = (const float*)d_in[3];
  const float* Dx2 = (const float*)d_in[4];
  const float* Dx3 = (const float*)d_in[5];
  const int* e0 = (const int*)d_in[6];
  const int* e1 = (const int*)d_in[7];
  const int* e2 = (const int*)d_in[8];
  const int* e3 = (const int*)d_in[9];
  const int* e4 = (const int*)d_in[10];
  const int* e5 = (const int*)d_in[11];
  const float* A   = (const float*)d_in[14];
  const float* Wnc = (const float*)d_in[16];
  const float* bnc = (const float*)d_in[17];
  const float* Wd  = (const float*)d_in[18];
  const float* bd  = (const float*)d_in[19];
  const float* W1  = (const float*)d_in[20];
  const float* b1  = (const float*)d_in[21];
  const float* W2  = (const float*)d_in[22];
  const float* Wj  = (const float*)d_in[23];
  const float* bj  = (const float*)d_in[24];
  (void)in_sizes; (void)n_in; (void)out_size; (void)ws_size;

  // ==== SCRATCH STRATEGY ====
  // d_out is 5120*10240 FLOAT32 = 209.7 MB and is FULLY rewritten by the final
  // kernel (k_dec). All large intermediates that die before k_dec live inside
  // d_out (first ~30.2 MB). d_ws holds only what k_dec reads (ud* split-bf16,
  // 3.93 MB) + weight staging (0.18 MB).
  char* ob = (char*)d_out;
  char* ws = (char*)d_ws;

  // ---- d_out zones ----
  float* xn_nc = (float*)(ob);                        // [0, 7,864,320)
  float* xn_d  = (float*)(ob + 7864320);              // [7,864,320, 11,796,480)
  float* cf_nc = (float*)(ob + 11796480);             // [11,796,480, 19,660,800)
  float* cf_d  = (float*)(ob + 19660800);             // [19,660,800, 23,592,960)
  // CSR zone at 23,592,960 (6.64 MB, dies after routing; mb aliases it after)
  int* cnt    = (int*)(ob + 23592960);
  int* incl   = (int*)(ob + 23592960 + 184320);
  int* bsum   = (int*)(ob + 23592960 + 368640);
  int* rowptr = (int*)(ob + 23592960 + 369664);
  int* cursor = (int*)(ob + 23592960 + 554240);
  int* csr    = (int*)(ob + 23592960 + 738560);       // ends at 30,229,760 << 209.7 MB
  unsigned int* mb = (unsigned int*)(ob + 23592960);  // 6.55 MB, after routing
  // attn outputs alias the xn_nc zone (xn dead after routing)
  unsigned short* ubf  = (unsigned short*)(ob);
  unsigned short* ubfT = (unsigned short*)(ob + 1310720);
  unsigned short* ibf  = (unsigned short*)(ob + 2621440);
  unsigned short* ibfT = (unsigned short*)(ob + 3276800);
  float* tu            = (float*)(ob + 3932160);
  float* ti            = (float*)(ob + 6553600);      // ends 7,864,320 (within xn_nc zone)

  // ---- d_ws zones (4.1 MB total) ----
  unsigned short* udUh = (unsigned short*)(ws);
  unsigned short* udUl = (unsigned short*)(ws + 1310720);
  unsigned short* udIh = (unsigned short*)(ws + 2621440);
  unsigned short* udIl = (unsigned short*)(ws + 3276800);
  unsigned short* WTnc_hi = (unsigned short*)(ws + 3932160);
  unsigned short* WTnc_lo = (unsigned short*)(ws + 4009984);
  unsigned short* WTd_hi  = (unsigned short*)(ws + 4087808);
  unsigned short* WTd_lo  = (unsigned short*)(ws + 4100096);

  // 1. weights prep
  k_prep<<<64, 256, 0, stream>>>(Wnc, Wd, WTnc_hi, WTnc_lo, WTd_hi, WTd_lo);

  // 2. encoders (linear + capsule norm), one launch per graph
  k_encoder<F_NC, KP_NC><<<160, 256, 0, stream>>>(NC1, WTnc_hi, WTnc_lo, bnc, xn_nc);
  k_encoder<F_NC, KP_NC><<<160, 256, 0, stream>>>(NC2, WTnc_hi, WTnc_lo, bnc, xn_nc + (size_t)N_NC * 64);
  k_encoder<F_NC, KP_NC><<<160, 256, 0, stream>>>(NC3, WTnc_hi, WTnc_lo, bnc, xn_nc + (size_t)2 * N_NC * 64);
  k_encoder<F_D, KP_D><<<80, 256, 0, stream>>>(Dx1, WTd_hi, WTd_lo, bd, xn_d);
  k_encoder<F_D, KP_D><<<80, 256, 0, stream>>>(Dx2, WTd_hi, WTd_lo, bd, xn_d + (size_t)N_D * 64);
  k_encoder<F_D, KP_D><<<80, 256, 0, stream>>>(Dx3, WTd_hi, WTd_lo, bd, xn_d + (size_t)2 * N_D * 64);

  // 3. CSR build (all 6 graphs)
  k_zero<<<180, 256, 0, stream>>>(cnt, TOT_NODES);
  k_hist<<<TOT_EDGES / 256, 256, 0, stream>>>(e0, e1, e2, e3, e4, e5, cnt);
  k_scan1<<<180, 256, 0, stream>>>(cnt, incl, bsum);
  k_scan2<<<1, 256, 0, stream>>>(bsum);
  k_scan3<<<180, 256, 0, stream>>>(incl, cnt, bsum, rowptr, cursor);
  k_scatter<<<TOT_EDGES / 256, 256, 0, stream>>>(e0, e1, e2, e3, e4, e5, cursor, csr);

  // 4. routing (3 iterations, node-local)
  k_route<N_NC><<<(3 * N_NC) / 8, 256, 0, stream>>>(xn_nc, cf_nc, rowptr, csr, 0);
  k_route<N_D><<<(3 * N_D) / 8, 256, 0, stream>>>(xn_d, cf_d, rowptr, csr, 3 * N_NC);

  // 5. mask bitmap (AFTER routing: mb aliases the CSR zone)
  k_mask<<<25600, 256, 0, stream>>>(A, mb);

  // 6. attention fuse + tu/ti (reads cf zone, writes into the xn zone)
  k_attn<<<N_NC / 4, 256, 0, stream>>>(cf_nc, N_NC, W1, b1, W2, Wj, bj, ubf, ubfT, tu);
  k_attn<<<N_D / 4, 256, 0, stream>>>(cf_d, N_D, W1, b1, W2, Wj, bj, ibf, ibfT, ti);

  // 7. joint update (reads d_out zones, writes ud* into d_ws)
  k_joint<false><<<N_NC / 16, 256, 0, stream>>>(ubf, ibf, ibfT, N_D, mb, tu, udUh, udUl);
  k_joint<true><<<N_D / 16, 256, 0, stream>>>(ibf, ubf, ubfT, N_NC, mb, ti, udIh, udIl);

  // 8. decoder (reads d_ws only; fully rewrites d_out as f32)
  k_dec<<<(N_D / 16) * (N_NC / 64) / 4, 256, 0, stream>>>(udIh, udIl, udUh, udUl, (float*)d_out);
}

// Round 9
// 1427.648 us; speedup vs baseline: 1.1337x; 1.1337x over previous
//
#include <hip/hip_runtime.h>
#include <hip/hip_bf16.h>
#include <stdint.h>

// ---------- types ----------
using bf16x8 = __attribute__((ext_vector_type(8))) short;
using f32x4  = __attribute__((ext_vector_type(4))) float;

__device__ __forceinline__ unsigned short f2b(float f) {
  unsigned u = __float_as_uint(f);
  u = u + 0x7FFFu + ((u >> 16) & 1u);   // RNE
  return (unsigned short)(u >> 16);
}
__device__ __forceinline__ float b2f(unsigned short s) {
  return __uint_as_float(((unsigned)s) << 16);
}

// ---------- problem constants ----------
#define N_NC 10240
#define N_D  5120
#define E_NC 327680
#define E_D  163840
#define F_NC 599
#define F_D  91
#define KP_NC 608
#define KP_D  96
#define TOT_NODES 46080               // 3*10240 + 3*5120
#define TOT_EDGES 1474560             // 3*E_NC + 3*E_D
#define MW 160                        // mask words per user row (5120/32)

// ---------- utility: zero an int buffer ----------
__global__ __launch_bounds__(256) void k_zero(int* p, int n) {
  int t = blockIdx.x * 256 + threadIdx.x;
  if (t < n) p[t] = 0;
}

// ---------- prep: transpose + bf16-split weights ----------
__global__ __launch_bounds__(256) void k_prep(const float* Wnc, const float* Wd,
                       unsigned short* WTnc_hi, unsigned short* WTnc_lo,
                       unsigned short* WTd_hi, unsigned short* WTd_lo) {
  int tid = blockIdx.x * blockDim.x + threadIdx.x;
  int stride = gridDim.x * blockDim.x;
  for (int i = tid; i < 64 * KP_NC; i += stride) {
    int d = i / KP_NC, k = i % KP_NC;
    float w = (k < F_NC) ? Wnc[k * 64 + d] : 0.0f;
    unsigned short h = f2b(w);
    WTnc_hi[i] = h;
    WTnc_lo[i] = f2b(w - b2f(h));
  }
  for (int i = tid; i < 64 * KP_D; i += stride) {
    int d = i / KP_D, k = i % KP_D;
    float w = (k < F_D) ? Wd[k * 64 + d] : 0.0f;
    unsigned short h = f2b(w);
    WTd_hi[i] = h;
    WTd_lo[i] = f2b(w - b2f(h));
  }
}

// ---------- encoder: h = x@W + b, capsule-l2norm -> xnorm (f32) ----------
template <int F, int KPAD>
__global__ __launch_bounds__(256) void k_encoder(const float* __restrict__ x,
    const unsigned short* __restrict__ WT_hi, const unsigned short* __restrict__ WT_lo,
    const float* __restrict__ bias, float* __restrict__ out) {
  int wave = threadIdx.x >> 6;
  int tile = blockIdx.x * 4 + wave;
  int l = threadIdx.x & 63;
  int h = l >> 4, r0 = l & 15;
  int m0 = tile * 16;

  f32x4 acc[4] = {{0,0,0,0},{0,0,0,0},{0,0,0,0},{0,0,0,0}};
  const float* xrow = x + (size_t)(m0 + r0) * F;

  for (int ks = 0; ks < KPAD / 32; ++ks) {
    int k0 = ks * 32 + h * 8;
    bf16x8 ah, al;
#pragma unroll
    for (int j = 0; j < 8; ++j) {
      int k = k0 + j;
      float v = (k < F) ? xrow[k] : 0.0f;
      unsigned short hb = f2b(v);
      ah[j] = (short)hb;
      al[j] = (short)f2b(v - b2f(hb));
    }
#pragma unroll
    for (int nt = 0; nt < 4; ++nt) {
      bf16x8 bh = *(const bf16x8*)(WT_hi + (nt * 16 + r0) * KPAD + k0);
      bf16x8 bl = *(const bf16x8*)(WT_lo + (nt * 16 + r0) * KPAD + k0);
      acc[nt] = __builtin_amdgcn_mfma_f32_16x16x32_bf16(ah, bh, acc[nt], 0, 0, 0);
      acc[nt] = __builtin_amdgcn_mfma_f32_16x16x32_bf16(ah, bl, acc[nt], 0, 0, 0);
      acc[nt] = __builtin_amdgcn_mfma_f32_16x16x32_bf16(al, bh, acc[nt], 0, 0, 0);
    }
  }
#pragma unroll
  for (int nt = 0; nt < 4; ++nt) {
    float bv = bias[nt * 16 + r0];
#pragma unroll
    for (int r = 0; r < 4; ++r) acc[nt][r] += bv;
  }
#pragma unroll
  for (int r = 0; r < 4; ++r) {
    float ss0 = acc[0][r] * acc[0][r] + acc[1][r] * acc[1][r];
    float ss1 = acc[2][r] * acc[2][r] + acc[3][r] * acc[3][r];
#pragma unroll
    for (int m = 1; m < 16; m <<= 1) { ss0 += __shfl_xor(ss0, m); ss1 += __shfl_xor(ss1, m); }
    float s0 = 1.0f / fmaxf(sqrtf(ss0), 1e-12f);
    float s1 = 1.0f / fmaxf(sqrtf(ss1), 1e-12f);
    float* o = out + (size_t)(m0 + 4 * h + r) * 64;
    o[ 0 + r0] = acc[0][r] * s0;
    o[16 + r0] = acc[1][r] * s0;
    o[32 + r0] = acc[2][r] * s1;
    o[48 + r0] = acc[3][r] * s1;
  }
}

// ---------- CSR build ----------
__device__ __forceinline__ void seg_decode(int t,
    const int* e0, const int* e1, const int* e2,
    const int* e3, const int* e4, const int* e5,
    const int** ep, int* el, int* noff, int* En) {
  if (t < 3 * E_NC) {
    int g = t / E_NC; *el = t - g * E_NC; *En = E_NC; *noff = g * N_NC;
    *ep = (g == 0) ? e0 : (g == 1) ? e1 : e2;
  } else {
    int u = t - 3 * E_NC;
    int g = u / E_D; *el = u - g * E_D; *En = E_D; *noff = 3 * N_NC + g * N_D;
    *ep = (g == 0) ? e3 : (g == 1) ? e4 : e5;
  }
}

__global__ __launch_bounds__(256) void k_hist(const int* e0, const int* e1, const int* e2,
                       const int* e3, const int* e4, const int* e5, int* cnt) {
  int t = blockIdx.x * blockDim.x + threadIdx.x;
  const int* ep; int el, noff, En;
  seg_decode(t, e0, e1, e2, e3, e4, e5, &ep, &el, &noff, &En);
  int trg = ep[En + el];
  atomicAdd(&cnt[noff + trg], 1);
}

__global__ __launch_bounds__(256) void k_scan1(const int* cnt, int* incl, int* bsum) {
  __shared__ int sh[256];
  int g = blockIdx.x * 256 + threadIdx.x;
  int v = cnt[g];
  sh[threadIdx.x] = v;
  __syncthreads();
  for (int off = 1; off < 256; off <<= 1) {
    int t = (threadIdx.x >= off) ? sh[threadIdx.x - off] : 0;
    __syncthreads();
    sh[threadIdx.x] += t;
    __syncthreads();
  }
  incl[g] = sh[threadIdx.x];
  if (threadIdx.x == 255) bsum[blockIdx.x] = sh[255];
}

__global__ __launch_bounds__(256) void k_scan2(int* bsum) {   // 1 block; 180 partials
  __shared__ int sh[256];
  int t = threadIdx.x;
  int v = (t < 180) ? bsum[t] : 0;
  sh[t] = v;
  __syncthreads();
  for (int off = 1; off < 256; off <<= 1) {
    int x = (t >= off) ? sh[t - off] : 0;
    __syncthreads();
    sh[t] += x;
    __syncthreads();
  }
  if (t < 180) bsum[t] = sh[t] - v;    // exclusive
}

__global__ __launch_bounds__(256) void k_scan3(const int* incl, const int* cnt,
                                               const int* bsum, int* rowptr, int* cursor) {
  int g = blockIdx.x * 256 + threadIdx.x;
  int x = incl[g] + bsum[blockIdx.x];
  rowptr[g + 1] = x;
  cursor[g] = x - cnt[g];
  if (g == 0) rowptr[0] = 0;
}

__global__ __launch_bounds__(256) void k_scatter(const int* e0, const int* e1, const int* e2,
                          const int* e3, const int* e4, const int* e5,
                          int* cursor, int* csr) {
  int t = blockIdx.x * blockDim.x + threadIdx.x;
  const int* ep; int el, noff, En;
  seg_decode(t, e0, e1, e2, e3, e4, e5, &ep, &el, &noff, &En);
  int src = ep[el];
  int trg = ep[En + el];
  int pos = atomicAdd(&cursor[noff + trg], 1);
  csr[pos] = src;
}

// ---------- routing: 3 iterations, node-local (32 lanes per node, 2 dims/lane) ----------
template <int NPG>
__global__ __launch_bounds__(256) void k_route(const float* __restrict__ xnorm, float* __restrict__ cfin,
    const int* __restrict__ row_ptr, const int* __restrict__ csr, int rpOff) {
  int node = (blockIdx.x * blockDim.x + threadIdx.x) >> 5;
  int q = threadIdx.x & 31;
  int graph = node / NPG;
  size_t gb32 = (size_t)graph * NPG * 32;
  int rp0 = row_ptr[rpOff + node], rp1 = row_ptr[rpOff + node + 1];
  const float2* xn2 = (const float2*)xnorm;
  float2 c = xn2[(size_t)node * 32 + q];
  for (int it = 0; it < 3; ++it) {
    float2 acc = c;
    for (int e = rp0; e < rp1; ++e) {
      int s = csr[e];
      float2 z = xn2[gb32 + (size_t)s * 32 + q];
      float part = z.x * c.x + z.y * c.y;
      part += __shfl_xor(part, 1);
      part += __shfl_xor(part, 2);
      part += __shfl_xor(part, 4);
      part += __shfl_xor(part, 8);
      float other = __shfl_xor(part, 16);
      float p = 1.0f / (1.0f + __expf(other - part));
      acc.x += p * z.x;
      acc.y += p * z.y;
    }
    float ss = acc.x * acc.x + acc.y * acc.y;
    ss += __shfl_xor(ss, 1);
    ss += __shfl_xor(ss, 2);
    ss += __shfl_xor(ss, 4);
    ss += __shfl_xor(ss, 8);
    float sc = 1.0f / fmaxf(sqrtf(ss), 1e-12f);
    c.x = acc.x * sc;
    c.y = acc.y * sc;
  }
  ((float2*)cfin)[(size_t)node * 32 + q] = c;
}

// ---------- attention fuse + tu = relu(fused@Wj+bj); emit bf16 row/col copies ----------
__global__ __launch_bounds__(256) void k_attn(const float* __restrict__ cfin, int n,
    const float* __restrict__ W1, const float* __restrict__ b1, const float* __restrict__ W2,
    const float* __restrict__ Wj, const float* __restrict__ bj,
    unsigned short* bfr, unsigned short* bfT, float* tu) {
  __shared__ float zs[4][3][64];
  __shared__ float fs[4][64];
  int wave = threadIdx.x >> 6, l = threadIdx.x & 63;
  int node = blockIdx.x * 4 + wave;
#pragma unroll
  for (int j = 0; j < 3; ++j)
    zs[wave][j][l] = cfin[((size_t)j * n + node) * 64 + l];
  __syncthreads();
  float w[3];
#pragma unroll
  for (int j = 0; j < 3; ++j) {
    float y = b1[l];
    for (int k = 0; k < 64; ++k) y += zs[wave][j][k] * W1[k * 64 + l];
    y = (y > 0.0f) ? y : 0.2f * y;
    float t = y * W2[l];
#pragma unroll
    for (int m = 1; m < 64; m <<= 1) t += __shfl_xor(t, m);
    w[j] = t;
  }
  float mx = fmaxf(w[0], fmaxf(w[1], w[2]));
  float e0 = __expf(w[0] - mx), e1 = __expf(w[1] - mx), e2 = __expf(w[2] - mx);
  float inv = 1.0f / (e0 + e1 + e2);
  float be0 = e0 * inv + 1e-6f, be1 = e1 * inv + 1e-6f, be2 = e2 * inv + 1e-6f;
  float bs = 1.0f / (be0 + be1 + be2);
  be0 *= bs; be1 *= bs; be2 *= bs;
  float o = be0 * zs[wave][0][l] + be1 * zs[wave][1][l] + be2 * zs[wave][2][l];
  fs[wave][l] = o;
  __syncthreads();
  bfr[(size_t)node * 64 + l] = f2b(o);
  bfT[(size_t)l * n + node] = f2b(o);
  float t = bj[l];
  for (int k = 0; k < 64; ++k) t += fs[wave][k] * Wj[k * 64 + l];
  tu[(size_t)node * 64 + l] = fmaxf(t, 0.0f);
}

// ---------- A>0 bitmask: mb[u][m/32] bit m%32 ----------
__global__ __launch_bounds__(256) void k_mask(const float* __restrict__ A, unsigned int* mb) {
  int wid = (blockIdx.x * blockDim.x + threadIdx.x) >> 6;   // global wave id
  int l = threadIdx.x & 63;
  int row = wid / 10, seg = wid % 10;                       // 512 cols per wave
  const float4* ap = (const float4*)(A + (size_t)row * 5120 + seg * 512 + l * 8);
  float4 v0 = ap[0], v1 = ap[1];
  unsigned b = (unsigned)(v0.x > 0.0f)       | ((unsigned)(v0.y > 0.0f) << 1)
             | ((unsigned)(v0.z > 0.0f) << 2) | ((unsigned)(v0.w > 0.0f) << 3)
             | ((unsigned)(v1.x > 0.0f) << 4) | ((unsigned)(v1.y > 0.0f) << 5)
             | ((unsigned)(v1.z > 0.0f) << 6) | ((unsigned)(v1.w > 0.0f) << 7);
  b |= ((unsigned)__shfl_xor((int)b, 1)) << 8;
  b |= ((unsigned)__shfl_xor((int)b, 2)) << 16;
  if ((l & 3) == 0) mb[row * MW + seg * 16 + (l >> 2)] = b;
}

// ---------- joint masked-softmax attention: ONE SWEEP, no max (scores bounded |s|<=2) ----------
// P = mask * exp(s); O += P@V (unnormalized); S += sum(P); out = tu + O/S (split-bf16).
// 4 waves split Nk; no in-loop barriers (P staging is intra-wave; DS pipe is in-order per wave).
template <bool MT>
__global__ __launch_bounds__(256) void k_joint(const unsigned short* __restrict__ qbf,
    const unsigned short* __restrict__ kbf, const unsigned short* __restrict__ vT, int Nk,
    const unsigned int* __restrict__ mb, const float* __restrict__ tu,
    unsigned short* outh, unsigned short* outl) {
  // pl: per-wave P staging, [16 rows][40 cols] ushort -> 80B row stride: 16B-aligned
  // b128 reads, <=2-way read bank conflicts.
  __shared__ __align__(16) unsigned short pl[4][16][40];
  __shared__ float oc[4][16][64];
  __shared__ float ssum[4][16];
  int wave = threadIdx.x >> 6, l = threadIdx.x & 63;
  int h = l >> 4, r0 = l & 15;
  int q0 = blockIdx.x * 16;
  int seg = Nk >> 2;
  int m_lo = wave * seg, m_hi = m_lo + seg;

  bf16x8 a0 = *(const bf16x8*)(qbf + (size_t)(q0 + r0) * 64 + h * 8);
  bf16x8 a1 = *(const bf16x8*)(qbf + (size_t)(q0 + r0) * 64 + 32 + h * 8);

  f32x4 o[4] = {{0,0,0,0},{0,0,0,0},{0,0,0,0},{0,0,0,0}};
  float ls[4] = {0.0f, 0.0f, 0.0f, 0.0f};

#pragma unroll 2
  for (int m0 = m_lo; m0 < m_hi; m0 += 32) {
    // scores: D[q=4h+r][k=r0 (s0) / r0+16 (s1)]
    f32x4 s0 = {0,0,0,0}, s1 = {0,0,0,0};
    bf16x8 b00 = *(const bf16x8*)(kbf + (size_t)(m0 + r0) * 64 + h * 8);
    bf16x8 b10 = *(const bf16x8*)(kbf + (size_t)(m0 + 16 + r0) * 64 + h * 8);
    bf16x8 b01 = *(const bf16x8*)(kbf + (size_t)(m0 + r0) * 64 + 32 + h * 8);
    bf16x8 b11 = *(const bf16x8*)(kbf + (size_t)(m0 + 16 + r0) * 64 + 32 + h * 8);
    s0 = __builtin_amdgcn_mfma_f32_16x16x32_bf16(a0, b00, s0, 0, 0, 0);
    s1 = __builtin_amdgcn_mfma_f32_16x16x32_bf16(a0, b10, s1, 0, 0, 0);
    s0 = __builtin_amdgcn_mfma_f32_16x16x32_bf16(a1, b01, s0, 0, 0, 0);
    s1 = __builtin_amdgcn_mfma_f32_16x16x32_bf16(a1, b11, s1, 0, 0, 0);

    unsigned w0 = 0, w1 = 0;
    if (MT) {
      w0 = mb[(size_t)(m0 + r0) * MW + (q0 >> 5)];
      w1 = mb[(size_t)(m0 + 16 + r0) * MW + (q0 >> 5)];
    }
#pragma unroll
    for (int r = 0; r < 4; ++r) {
      float p0, p1;
      if (MT) {
        int bit = (q0 & 31) + 4 * h + r;
        p0 = ((w0 >> bit) & 1u) ? __expf(s0[r]) : 0.0f;
        p1 = ((w1 >> bit) & 1u) ? __expf(s1[r]) : 0.0f;
      } else {
        unsigned wr = mb[(size_t)(q0 + 4 * h + r) * MW + (m0 >> 5)];
        p0 = ((wr >> r0) & 1u) ? __expf(s0[r]) : 0.0f;
        p1 = ((wr >> (r0 + 16)) & 1u) ? __expf(s1[r]) : 0.0f;
      }
      ls[r] += p0 + p1;
      pl[wave][4 * h + r][r0]      = f2b(p0);
      pl[wave][4 * h + r][r0 + 16] = f2b(p1);
    }
    // intra-wave LDS transpose: per-wave DS ops are in-order; compiler inserts the
    // lgkmcnt wait for the dependent read below.
    bf16x8 pa = *(const bf16x8*)(&pl[wave][r0][h * 8]);
#pragma unroll
    for (int nt = 0; nt < 4; ++nt) {
      bf16x8 bv = *(const bf16x8*)(vT + (size_t)(nt * 16 + r0) * Nk + m0 + h * 8);
      o[nt] = __builtin_amdgcn_mfma_f32_16x16x32_bf16(pa, bv, o[nt], 0, 0, 0);
    }
  }

  // reduce per-row expsum across the 16 k-lanes
#pragma unroll
  for (int r = 0; r < 4; ++r) {
#pragma unroll
    for (int m = 1; m < 16; m <<= 1) ls[r] += __shfl_xor(ls[r], m);
  }
  if (r0 == 0) {
#pragma unroll
    for (int r = 0; r < 4; ++r) ssum[wave][4 * h + r] = ls[r];
  }
#pragma unroll
  for (int nt = 0; nt < 4; ++nt)
#pragma unroll
    for (int r = 0; r < 4; ++r)
      oc[wave][4 * h + r][nt * 16 + r0] = o[nt][r];
  __syncthreads();
  for (int e = threadIdx.x; e < 1024; e += 256) {
    int row = e >> 6, col = e & 63;
    float v = oc[0][row][col] + oc[1][row][col] + oc[2][row][col] + oc[3][row][col];
    float S = ssum[0][row] + ssum[1][row] + ssum[2][row] + ssum[3][row];
    v = v / fmaxf(S, 1e-30f) + tu[(size_t)(q0 + row) * 64 + col];
    unsigned short hb = f2b(v);
    outh[(size_t)(q0 + row) * 64 + col] = hb;
    outl[(size_t)(q0 + row) * 64 + col] = f2b(v - b2f(hb));
  }
}

// ---------- decoder: out[i][u] = sum_d I[i][d]*U[u][d], split-bf16 inputs, FLOAT32 out ----------
__global__ __launch_bounds__(256) void k_dec(const unsigned short* __restrict__ Ih,
    const unsigned short* __restrict__ Il,
    const unsigned short* __restrict__ Uh, const unsigned short* __restrict__ Ul,
    float* __restrict__ out) {
  int w = (blockIdx.x * blockDim.x + threadIdx.x) >> 6;
  int l = threadIdx.x & 63, h = l >> 4, r0 = l & 15;
  int i0 = (w / 160) * 16, u0 = (w % 160) * 64;
  size_t abase = (size_t)(i0 + r0) * 64 + h * 8;
  bf16x8 a0h = *(const bf16x8*)(Ih + abase);
  bf16x8 a1h = *(const bf16x8*)(Ih + abase + 32);
  bf16x8 a0l = *(const bf16x8*)(Il + abase);
  bf16x8 a1l = *(const bf16x8*)(Il + abase + 32);
#pragma unroll
  for (int nt = 0; nt < 4; ++nt) {
    size_t bbase = (size_t)(u0 + nt * 16 + r0) * 64 + h * 8;
    bf16x8 b0h = *(const bf16x8*)(Uh + bbase);
    bf16x8 b1h = *(const bf16x8*)(Uh + bbase + 32);
    bf16x8 b0l = *(const bf16x8*)(Ul + bbase);
    bf16x8 b1l = *(const bf16x8*)(Ul + bbase + 32);
    f32x4 acc = {0,0,0,0};
    acc = __builtin_amdgcn_mfma_f32_16x16x32_bf16(a0h, b0h, acc, 0, 0, 0);
    acc = __builtin_amdgcn_mfma_f32_16x16x32_bf16(a1h, b1h, acc, 0, 0, 0);
    acc = __builtin_amdgcn_mfma_f32_16x16x32_bf16(a0h, b0l, acc, 0, 0, 0);
    acc = __builtin_amdgcn_mfma_f32_16x16x32_bf16(a1h, b1l, acc, 0, 0, 0);
    acc = __builtin_amdgcn_mfma_f32_16x16x32_bf16(a0l, b0h, acc, 0, 0, 0);
    acc = __builtin_amdgcn_mfma_f32_16x16x32_bf16(a1l, b1h, acc, 0, 0, 0);
#pragma unroll
    for (int r = 0; r < 4; ++r)
      out[(size_t)(i0 + 4 * h + r) * 10240 + u0 + nt * 16 + r0] = acc[r];
  }
}

// ---------- host ----------
extern "C" void kernel_launch(void* const* d_in, const int* in_sizes, int n_in,
                              void* d_out, int out_size, void* d_ws, size_t ws_size,
                              hipStream_t stream) {
  const float* NC1 = (const float*)d_in[0];
  const float* NC2 = (const float*)d_in[1];
  const float* NC3 = (const float*)d_in[2];
  const float* Dx1 = (const float*)d_in[3];
  const float* Dx2 = (const float*)d_in[4];
  const float* Dx3 = (const float*)d_in[5];
  const int* e0 = (const int*)d_in[6];
  const int* e1 = (const int*)d_in[7];
  const int* e2 = (const int*)d_in[8];
  const int* e3 = (const int*)d_in[9];
  const int* e4 = (const int*)d_in[10];
  const int* e5 = (const int*)d_in[11];
  const float* A   = (const float*)d_in[14];
  const float* Wnc = (const float*)d_in[16];
  const float* bnc = (const float*)d_in[17];
  const float* Wd  = (const float*)d_in[18];
  const float* bd  = (const float*)d_in[19];
  const float* W1  = (const float*)d_in[20];
  const float* b1  = (const float*)d_in[21];
  const float* W2  = (const float*)d_in[22];
  const float* Wj  = (const float*)d_in[23];
  const float* bj  = (const float*)d_in[24];
  (void)in_sizes; (void)n_in; (void)out_size; (void)ws_size;

  // ==== SCRATCH STRATEGY ====
  // d_out is 5120*10240 FLOAT32 = 209.7 MB and is FULLY rewritten by the final
  // kernel (k_dec). All large intermediates that die before k_dec live inside
  // d_out (first ~30.2 MB). d_ws holds only what k_dec reads (ud* split-bf16,
  // 3.93 MB) + weight staging (0.18 MB).
  char* ob = (char*)d_out;
  char* ws = (char*)d_ws;

  // ---- d_out zones ----
  float* xn_nc = (float*)(ob);                        // [0, 7,864,320)
  float* xn_d  = (float*)(ob + 7864320);              // [7,864,320, 11,796,480)
  float* cf_nc = (float*)(ob + 11796480);             // [11,796,480, 19,660,800)
  float* cf_d  = (float*)(ob + 19660800);             // [19,660,800, 23,592,960)
  // CSR zone at 23,592,960 (6.64 MB, dies after routing; mb aliases it after)
  int* cnt    = (int*)(ob + 23592960);
  int* incl   = (int*)(ob + 23592960 + 184320);
  int* bsum   = (int*)(ob + 23592960 + 368640);
  int* rowptr = (int*)(ob + 23592960 + 369664);
  int* cursor = (int*)(ob + 23592960 + 554240);
  int* csr    = (int*)(ob + 23592960 + 738560);       // ends at 30,229,760 << 209.7 MB
  unsigned int* mb = (unsigned int*)(ob + 23592960);  // 6.55 MB, after routing
  // attn outputs alias the xn_nc zone (xn dead after routing)
  unsigned short* ubf  = (unsigned short*)(ob);
  unsigned short* ubfT = (unsigned short*)(ob + 1310720);
  unsigned short* ibf  = (unsigned short*)(ob + 2621440);
  unsigned short* ibfT = (unsigned short*)(ob + 3276800);
  float* tu            = (float*)(ob + 3932160);
  float* ti            = (float*)(ob + 6553600);      // ends 7,864,320 (within xn_nc zone)

  // ---- d_ws zones (4.1 MB total) ----
  unsigned short* udUh = (unsigned short*)(ws);
  unsigned short* udUl = (unsigned short*)(ws + 1310720);
  unsigned short* udIh = (unsigned short*)(ws + 2621440);
  unsigned short* udIl = (unsigned short*)(ws + 3276800);
  unsigned short* WTnc_hi = (unsigned short*)(ws + 3932160);
  unsigned short* WTnc_lo = (unsigned short*)(ws + 4009984);
  unsigned short* WTd_hi  = (unsigned short*)(ws + 4087808);
  unsigned short* WTd_lo  = (unsigned short*)(ws + 4100096);

  // 1. weights prep
  k_prep<<<64, 256, 0, stream>>>(Wnc, Wd, WTnc_hi, WTnc_lo, WTd_hi, WTd_lo);

  // 2. encoders (linear + capsule norm), one launch per graph
  k_encoder<F_NC, KP_NC><<<160, 256, 0, stream>>>(NC1, WTnc_hi, WTnc_lo, bnc, xn_nc);
  k_encoder<F_NC, KP_NC><<<160, 256, 0, stream>>>(NC2, WTnc_hi, WTnc_lo, bnc, xn_nc + (size_t)N_NC * 64);
  k_encoder<F_NC, KP_NC><<<160, 256, 0, stream>>>(NC3, WTnc_hi, WTnc_lo, bnc, xn_nc + (size_t)2 * N_NC * 64);
  k_encoder<F_D, KP_D><<<80, 256, 0, stream>>>(Dx1, WTd_hi, WTd_lo, bd, xn_d);
  k_encoder<F_D, KP_D><<<80, 256, 0, stream>>>(Dx2, WTd_hi, WTd_lo, bd, xn_d + (size_t)N_D * 64);
  k_encoder<F_D, KP_D><<<80, 256, 0, stream>>>(Dx3, WTd_hi, WTd_lo, bd, xn_d + (size_t)2 * N_D * 64);

  // 3. CSR build (all 6 graphs)
  k_zero<<<180, 256, 0, stream>>>(cnt, TOT_NODES);
  k_hist<<<TOT_EDGES / 256, 256, 0, stream>>>(e0, e1, e2, e3, e4, e5, cnt);
  k_scan1<<<180, 256, 0, stream>>>(cnt, incl, bsum);
  k_scan2<<<1, 256, 0, stream>>>(bsum);
  k_scan3<<<180, 256, 0, stream>>>(incl, cnt, bsum, rowptr, cursor);
  k_scatter<<<TOT_EDGES / 256, 256, 0, stream>>>(e0, e1, e2, e3, e4, e5, cursor, csr);

  // 4. routing (3 iterations, node-local)
  k_route<N_NC><<<(3 * N_NC) / 8, 256, 0, stream>>>(xn_nc, cf_nc, rowptr, csr, 0);
  k_route<N_D><<<(3 * N_D) / 8, 256, 0, stream>>>(xn_d, cf_d, rowptr, csr, 3 * N_NC);

  // 5. mask bitmap (AFTER routing: mb aliases the CSR zone)
  k_mask<<<25600, 256, 0, stream>>>(A, mb);

  // 6. attention fuse + tu/ti (reads cf zone, writes into the xn zone)
  k_attn<<<N_NC / 4, 256, 0, stream>>>(cf_nc, N_NC, W1, b1, W2, Wj, bj, ubf, ubfT, tu);
  k_attn<<<N_D / 4, 256, 0, stream>>>(cf_d, N_D, W1, b1, W2, Wj, bj, ibf, ibfT, ti);

  // 7. joint update (reads d_out zones, writes ud* into d_ws)
  k_joint<false><<<N_NC / 16, 256, 0, stream>>>(ubf, ibf, ibfT, N_D, mb, tu, udUh, udUl);
  k_joint<true><<<N_D / 16, 256, 0, stream>>>(ibf, ubf, ubfT, N_NC, mb, ti, udIh, udIl);

  // 8. decoder (reads d_ws only; fully rewrites d_out as f32)
  k_dec<<<(N_D / 16) * (N_NC / 64) / 4, 256, 0, stream>>>(udIh, udIl, udUh, udUl, (float*)d_out);
}